// Round 10
// baseline (1506.992 us; speedup 1.0000x reference)
//
#include <hip/hip_runtime.h>
#include <math.h>

#define BB 32
#define TT 2048
#define HH 128

typedef float f32x2 __attribute__((ext_vector_type(2)));

// LDS-only barrier: waits LDS ops (lgkmcnt), leaves global loads/stores in
// flight across the barrier.
#define LDS_BARRIER() asm volatile("s_waitcnt lgkmcnt(0)\n\ts_barrier" ::: "memory")

// DPP helper: any DPP ctrl (quad_perm 0x00-0xFF, row_ror 0x120+n, ...).
#define QPERM_F(v, CTRL)                                                      \
  __int_as_float(__builtin_amdgcn_update_dpp(                                 \
      0, __float_as_int(v), (CTRL), 0xF, 0xF, true))

// ds_swizzle pattern must be a literal constant at the builtin call site.
template <int OFFS>
__device__ __forceinline__ float swz_xor(float v) {
  return __int_as_float(__builtin_amdgcn_ds_swizzle(__float_as_int(v), OFFS));
}

// Merging butterfly stage: lanes with bit=0 end with x summed over the lane
// pair; lanes with bit=1 end with y summed. (proven in v6/R6-R8)
#define MERGE_DPP(x, y, bit, CTRL)                                            \
  ({                                                                          \
    float _k = (bit) ? (y) : (x);                                             \
    float _s = (bit) ? (x) : (y);                                             \
    _k + QPERM_F(_s, CTRL);                                                   \
  })
#define MERGE_SWZ(x, y, bit, OFFS)                                            \
  ({                                                                          \
    float _k = (bit) ? (y) : (x);                                             \
    float _s = (bit) ? (x) : (y);                                             \
    _k + swz_xor<OFFS>(_s);                                                   \
  })

__device__ __forceinline__ float tanh_fast(float s) {
  float ax = fabsf(s);
  float e = __expf(-2.0f * ax);
  float th = (1.0f - e) * __builtin_amdgcn_rcpf(1.0f + e);
  return copysignf(th, s);
}

// ---------------------------------------------------------------------------
// proj kernel: out[r, :] = emb[tokens[r]] @ Wx0 + b0   (layer-0 input proj)
// ---------------------------------------------------------------------------
template <bool GATHER>
__global__ __launch_bounds__(256) void proj_kernel(
    const float* __restrict__ src, const int* __restrict__ tokens,
    const float* __restrict__ W, const float* __restrict__ bias,
    float* __restrict__ out) {
  const int tid = threadIdx.x;
  const int jj = tid & 31;
  const int rr = tid >> 5;
  const int base = blockIdx.x * 64;

  __shared__ __align__(16) float srow[64][HH];
  __shared__ int stok[64];

  if (GATHER) {
    if (tid < 64) stok[tid] = tokens[base + tid];
    __syncthreads();
  }

#pragma unroll
  for (int i = 0; i < 8; ++i) {
    int idx = tid + i * 256;
    int row = idx >> 5;
    int c4 = idx & 31;
    const float* s = GATHER ? (src + (size_t)stok[row] * HH)
                            : (src + (size_t)(base + row) * HH);
    *(float4*)&srow[row][c4 * 4] = *(const float4*)&s[c4 * 4];
  }
  __syncthreads();

  float4 b4 = *(const float4*)&bias[jj * 4];
  float4 acc[8];
#pragma unroll
  for (int i = 0; i < 8; ++i) acc[i] = b4;

  for (int k = 0; k < HH; ++k) {
    float4 w4 = *(const float4*)&W[k * HH + jj * 4];
#pragma unroll
    for (int i = 0; i < 8; ++i) {
      float e = srow[rr * 8 + i][k];
      acc[i].x += e * w4.x;
      acc[i].y += e * w4.y;
      acc[i].z += e * w4.z;
      acc[i].w += e * w4.w;
    }
  }

#pragma unroll
  for (int i = 0; i < 8; ++i) {
    int row = base + rr * 8 + i;
    *(float4*)&out[(size_t)row * HH + jj * 4] = acc[i];
  }
}

// ---------------------------------------------------------------------------
// fused rnn kernel v10: f32 everywhere (R9: f16 h accumulates 0.46 absmax
// through 2048 recurrent steps — precision path closed), 1024 threads so the
// per-thread weight need fits UNDER the RA's ~88-reg comfort line.
//
// R6-R8 model: at 512 thr the 96 f32 weights/thread were kept in AGPRs and
// re-read per use (v_accvgpr_read): VALU 840cy/step = (95 intended + ~96
// AGPR reads) x 2cy x 2 waves/SIMD. No attribute/pin changes that; only
// lowering NEED does. weights/thread = 49152/threads -> 1024 thr = 48 floats
// (24 f32x2) + ~35 state ~= 85 regs, under the wall.
//
// Thread (jg = tid>>5 -> cols 4jg..4jg+3; p = tid&31 -> k in [4p,4p+4)):
//   - 24 f32x2 weight regs (Wh0/Wx1/Wh1), 24 pk_fma/step
//   - reads 4 h0 + 4 h1 floats (2x ds_read_b128, conflict-free / broadcast)
//   - merge-butterfly reduce over 32 k-lanes: bit0 col-parity (dpp xor1),
//     bit1 col-pair (dpp xor2), bit2 layer (swz xor4), + xor8 (dpp row_ror:8)
//     + xor16 (swz 0x401F) dup folds. Same bit-roles as proven v6, one extra
//     fold stage. Lane ends with (layer=lb2, col=4jg+2lb1+lb0), dup x4.
//   - t-loop unrolled x2: static double-buffer indices, no pr/pw math.
// waves_per_eu(4,4): 16 waves = 1 block/CU, VGPR cap 128.
// ---------------------------------------------------------------------------
__global__ __launch_bounds__(1024)
__attribute__((amdgpu_waves_per_eu(4, 4))) void rnn_fused_kernel(
    const float* __restrict__ xp0, float* __restrict__ out,
    const float* __restrict__ Wh0, const float* __restrict__ Wx1,
    const float* __restrict__ Wh1, const float* __restrict__ bias1,
    const int* __restrict__ tokens) {
  const int b = blockIdx.x;
  const int tid = threadIdx.x;
  const int lane = tid & 63;
  const int p = tid & 31;   // k-split 0..31, k in [4p, 4p+4)
  const int jg = tid >> 5;  // col-group 0..31
  const int lb0 = p & 1;
  const int lb1 = (p >> 1) & 1;
  const int lb2 = (p >> 2) & 1;               // layer select after reduce
  const int mycol = 4 * jg + 2 * lb1 + lb0;   // owned col after reduce

  // weights: rows 4p..4p+3, cols 4jg..4jg+3 of Wh0 / Wx1 / Wh1 (48 floats)
  f32x2 w0a[4], w0b[4], wxa[4], wxb[4], wha[4], whb[4];
#pragma unroll
  for (int i = 0; i < 4; ++i) {
    int row = 4 * p + i;
    float4 v0 = *(const float4*)&Wh0[row * HH + 4 * jg];
    float4 v1 = *(const float4*)&Wx1[row * HH + 4 * jg];
    float4 v2 = *(const float4*)&Wh1[row * HH + 4 * jg];
    w0a[i] = (f32x2){v0.x, v0.y};
    w0b[i] = (f32x2){v0.z, v0.w};
    wxa[i] = (f32x2){v1.x, v1.y};
    wxb[i] = (f32x2){v1.z, v1.w};
    wha[i] = (f32x2){v2.x, v2.y};
    whb[i] = (f32x2){v2.z, v2.w};
  }
  const float biasv = bias1[mycol];

  // mask bitmask: lane l holds bits for t in [32l, 32l+32); replicated/wave.
  const int* tok = tokens + b * TT;
  unsigned bits = 0;
#pragma unroll
  for (int i = 0; i < 8; ++i) {
    int4 tk = *(const int4*)&tok[lane * 32 + i * 4];
    bits |= (unsigned)(tk.x != 0) << (i * 4 + 0);
    bits |= (unsigned)(tk.y != 0) << (i * 4 + 1);
    bits |= (unsigned)(tk.z != 0) << (i * 4 + 2);
    bits |= (unsigned)(tk.w != 0) << (i * 4 + 3);
  }

  // double-buffered h, contiguous f32 (reads: b128 at 16p -> conflict-free /
  // same-addr broadcast across wave halves; writes: 16B-contiguous groups)
  __shared__ __align__(16) float h0s[2][HH];
  __shared__ __align__(16) float h1s[2][HH];
  if (tid < HH) {
    h0s[0][tid] = 0.0f;  // h0[-1]
    h1s[0][tid] = 0.0f;  // h1[-2]
  }

  const float* xp = xp0 + (size_t)b * TT * HH + mycol;
  float* outp = out + (size_t)b * TT * HH + mycol;

  float h = 0.0f;  // carried state for my (layer, col)
  float xc = xp[0];
  float xn = xp[HH];
  LDS_BARRIER();

#define RNN_STEP(HRD0, HRD1, HWR0, HWR1, T, XC)                               \
  {                                                                           \
    float4 q = *(const float4*)&(HRD0)[4 * p];                                \
    float4 g = *(const float4*)&(HRD1)[4 * p];                                \
    f32x2 a0a = {0.f, 0.f}, a0b = {0.f, 0.f};                                 \
    f32x2 a1a = {0.f, 0.f}, a1b = {0.f, 0.f};                                 \
    a0a += q.x * w0a[0]; a0b += q.x * w0b[0];                                 \
    a1a += q.x * wxa[0]; a1b += q.x * wxb[0];                                 \
    a1a += g.x * wha[0]; a1b += g.x * whb[0];                                 \
    a0a += q.y * w0a[1]; a0b += q.y * w0b[1];                                 \
    a1a += q.y * wxa[1]; a1b += q.y * wxb[1];                                 \
    a1a += g.y * wha[1]; a1b += g.y * whb[1];                                 \
    a0a += q.z * w0a[2]; a0b += q.z * w0b[2];                                 \
    a1a += q.z * wxa[2]; a1b += q.z * wxb[2];                                 \
    a1a += g.z * wha[2]; a1b += g.z * whb[2];                                 \
    a0a += q.w * w0a[3]; a0b += q.w * w0b[3];                                 \
    a1a += q.w * wxa[3]; a1b += q.w * wxb[3];                                 \
    a1a += g.w * wha[3]; a1b += g.w * whb[3];                                 \
    float m0 = MERGE_DPP(a0a.x, a0a.y, lb0, 0xB1);                            \
    float m1 = MERGE_DPP(a0b.x, a0b.y, lb0, 0xB1);                            \
    float m2 = MERGE_DPP(a1a.x, a1a.y, lb0, 0xB1);                            \
    float m3 = MERGE_DPP(a1b.x, a1b.y, lb0, 0xB1);                            \
    float n0 = MERGE_DPP(m0, m1, lb1, 0x4E);                                  \
    float n1 = MERGE_DPP(m2, m3, lb1, 0x4E);                                  \
    float r = MERGE_SWZ(n0, n1, lb2, 0x101F); /* layer (xor4) */              \
    r += QPERM_F(r, 0x128);      /* xor8: row_ror:8 */                        \
    r += swz_xor<0x401F>(r);     /* xor16 */                                  \
    float s = r + (lb2 ? biasv : (XC));                                       \
    unsigned wd0 = (unsigned)__builtin_amdgcn_readlane((int)bits, (T) >> 5);  \
    int mk0 = (wd0 >> ((T)&31)) & 1;                                          \
    int mk1 = 0;                                                              \
    if ((T) > 0) {                                                            \
      unsigned wd1 =                                                          \
          (unsigned)__builtin_amdgcn_readlane((int)bits, ((T)-1) >> 5);       \
      mk1 = (wd1 >> (((T)-1) & 31)) & 1;                                      \
    }                                                                         \
    int mm = lb2 ? mk1 : mk0;                                                 \
    float th = tanh_fast(s);                                                  \
    h = mm ? th : h;                                                          \
    if ((p & 24) == 0) { /* 8 writer lanes per 32-half */                     \
      if (lb2) {                                                              \
        (HWR1)[mycol] = h; /* publish h1[T-1] */                              \
        if ((T) > 0) outp[(size_t)((T)-1) * HH] = h;                          \
      } else {                                                                \
        (HWR0)[mycol] = h; /* publish h0[T] */                                \
      }                                                                       \
    }                                                                         \
    LDS_BARRIER();                                                            \
  }

  for (int t0 = 0; t0 < TT; t0 += 2) {
    float x2 = 0.0f, x3 = 0.0f;
    if (t0 + 2 < TT) x2 = xp[(size_t)(t0 + 2) * HH];
    if (t0 + 3 < TT) x3 = xp[(size_t)(t0 + 3) * HH];
    RNN_STEP(h0s[0], h1s[0], h0s[1], h1s[1], t0, xc)
    RNN_STEP(h0s[1], h1s[1], h0s[0], h1s[0], t0 + 1, xn)
    xc = x2;
    xn = x3;
  }
#undef RNN_STEP

  // tail superstep (t == TT): h1[TT-1] from h0[TT-1] and h1[TT-2]; last loop
  // step (t=2047, odd) read buf1 and wrote buf0 -> both live in buf 0.
  {
    float4 q = *(const float4*)&h0s[0][4 * p];
    float4 g = *(const float4*)&h1s[0][4 * p];
    f32x2 a1a = {0.f, 0.f}, a1b = {0.f, 0.f};
    a1a += q.x * wxa[0]; a1b += q.x * wxb[0];
    a1a += g.x * wha[0]; a1b += g.x * whb[0];
    a1a += q.y * wxa[1]; a1b += q.y * wxb[1];
    a1a += g.y * wha[1]; a1b += g.y * whb[1];
    a1a += q.z * wxa[2]; a1b += q.z * wxb[2];
    a1a += g.z * wha[2]; a1b += g.z * whb[2];
    a1a += q.w * wxa[3]; a1b += q.w * wxb[3];
    a1a += g.w * wha[3]; a1b += g.w * whb[3];

    float m2 = MERGE_DPP(a1a.x, a1a.y, lb0, 0xB1);
    float m3 = MERGE_DPP(a1b.x, a1b.y, lb0, 0xB1);
    float n1 = MERGE_DPP(m2, m3, lb1, 0x4E);
    float r = n1 + swz_xor<0x101F>(n1);  // plain folds: only L1 values exist
    r += QPERM_F(r, 0x128);
    r += swz_xor<0x401F>(r);
    float s = r + biasv;

    const int t1 = TT - 1;
    unsigned wd1 = (unsigned)__builtin_amdgcn_readlane((int)bits, t1 >> 5);
    int mk1 = (wd1 >> (t1 & 31)) & 1;
    if (lb2) {  // lanes whose carried h is the h1 state
      float th = tanh_fast(s);
      float hv = mk1 ? th : h;
      if ((p & 24) == 0) outp[(size_t)t1 * HH] = hv;
    }
  }
}

extern "C" void kernel_launch(void* const* d_in, const int* in_sizes, int n_in,
                              void* d_out, int out_size, void* d_ws,
                              size_t ws_size, hipStream_t stream) {
  const int* tokens = (const int*)d_in[0];
  const float* emb = (const float*)d_in[1];
  const float* Wx0 = (const float*)d_in[2];
  const float* Wh0 = (const float*)d_in[3];
  const float* b0 = (const float*)d_in[4];
  const float* Wx1 = (const float*)d_in[5];
  const float* Wh1 = (const float*)d_in[6];
  const float* b1 = (const float*)d_in[7];
  float* out = (float*)d_out;
  float* ws = (float*)d_ws;  // 32 MB: xp0

  const int rows = BB * TT;           // 65536
  const int proj_blocks = rows / 64;  // 1024

  proj_kernel<true><<<proj_blocks, 256, 0, stream>>>(emb, tokens, Wx0, b0, ws);
  rnn_fused_kernel<<<BB, 1024, 0, stream>>>(ws, out, Wh0, Wx1, Wh1, b1,
                                            tokens);
}